// Round 18
// baseline (410.094 us; speedup 1.0000x reference)
//
#include <hip/hip_runtime.h>

// VposeFiled_Vjmlp: RFF encode + 80-group weight-norm MLP chain (480->512->512->256->6)
// R18: mlp M=128 rows/block with 16 WAVES (1024 thr, 1 block/CU, 4 waves/SIMD —
//      same TLP as the 233us R13/R16 structure) -> B-TCP traffic HALVES
//      (3.2GB -> 1.6GB, was the co-largest pipe). N=512 layers: 16 col strips
//      (NT=1, acc[4]=64 AGPR); N=256: 8 strips x 2 row halves (acc[2]).
//      R17's A-dbuf reverted (3rd null; mild spill). prep_all unchanged (R16).

typedef __attribute__((ext_vector_type(8)))  short short8;
typedef __attribute__((ext_vector_type(4)))  float f32x4;
typedef __attribute__((ext_vector_type(16))) float f32x16;
typedef __attribute__((ext_vector_type(2)))  unsigned int uint2v;

#define VJ    80
#define FS    480
#define HD2   512
#define HD    256
#define BATCH 2048
#define SMLP  520   // stride ushorts: 260 dw ≡ 4 (mod 32) -> ~2-way on 32-row b128 reads

static __device__ __forceinline__ unsigned short f2bf(float f) {
  unsigned int u = __builtin_bit_cast(unsigned int, f);
  u += 0x7FFFu + ((u >> 16) & 1u);          // round-to-nearest-even
  return (unsigned short)(u >> 16);
}

// ---------------------------------------------------------------------------
// Merged prep (1024 thr). 13-chunks: 8 weight-blocks + 5 prep_x-blocks.
// Weight blocks: [0,1280) W0, [1280,2560) W1, [2560,3200) W2 (32x32 frag pack),
// [3200,3280) W3 (16x16 frags, cols padded 6->16).
// 32x32 frag(nt,ks) = 512 ushorts: lane l elem j = W[nt*32+(l&31)][ks*16+(l>>5)*8+j]
// ---------------------------------------------------------------------------
template<int K, int RPG>
static __device__ __forceinline__ void wfrag32_body(
    int blk, const float* __restrict__ v, const float* __restrict__ gain,
    unsigned short* __restrict__ dst, float* sV, float* sScale) {
  constexpr int KS = K / 16;
  constexpr int KP = K + 4;
  const int t  = threadIdx.x;               // 0..1023
  const int n0 = blk * 32;
  const int g  = n0 / RPG;
  const int nt = (n0 % RPG) >> 5;

  const f32x4* v4 = (const f32x4*)(v + (size_t)n0 * K);
  for (int idx = t; idx < 32 * K / 4; idx += 1024) {
    int row = idx / (K / 4), rem = idx - row * (K / 4);
    *(f32x4*)&sV[row * KP + rem * 4] = v4[idx];
  }
  __syncthreads();

  const int wave = t >> 6, lane = t & 63;   // 16 waves
  for (int r = wave; r < 32; r += 16) {
    float s = 0.f;
    for (int k = lane; k < K; k += 64) { float x = sV[r * KP + k]; s += x * x; }
    #pragma unroll
    for (int off = 32; off > 0; off >>= 1) s += __shfl_down(s, off);
    if (lane == 0) sScale[r] = gain[n0 + r] / sqrtf(s);
  }
  __syncthreads();

  unsigned short* db = dst + (size_t)g * RPG * K + (size_t)nt * KS * 512;
  for (int o = t; o < KS * 64; o += 1024) {
    int ks = o >> 6, l = o & 63;
    int nl = l & 31, k0 = ks * 16 + ((l >> 5) << 3);
    float sc = sScale[nl];
    short8 pk;
    #pragma unroll
    for (int j = 0; j < 8; ++j) pk[j] = (short)f2bf(sV[nl * KP + k0 + j] * sc);
    *(short8*)&db[(size_t)ks * 512 + l * 8] = pk;
  }
}

// W3 per-group: 6 rows, K=256 -> 8 frags (16x16x32), cols padded to 16 w/ zeros.
static __device__ __forceinline__ void w3frag_body(
    int gidx, const float* __restrict__ v3, const float* __restrict__ g3,
    unsigned short* __restrict__ W3f, float* sV, float* sScale) {
  const int t = threadIdx.x;
  const f32x4* v4 = (const f32x4*)(v3 + (size_t)gidx * 6 * 256);
  if (t < 384) {
    int row = t >> 6, rem = t & 63;
    *(f32x4*)&sV[row * 260 + rem * 4] = v4[t];
  }
  __syncthreads();
  const int wave = t >> 6, lane = t & 63;
  if (wave < 6) {
    float s = 0.f;
    #pragma unroll
    for (int k = 0; k < 4; ++k) { float x = sV[wave * 260 + lane + k * 64]; s += x * x; }
    #pragma unroll
    for (int off = 32; off > 0; off >>= 1) s += __shfl_down(s, off);
    if (lane == 0) sScale[wave] = g3[gidx * 6 + wave] / sqrtf(s);
  }
  __syncthreads();
  if (t < 512) {
    int ks = t >> 6, l = t & 63;
    int c = l & 15, k0 = ks * 32 + ((l >> 4) << 3);
    short8 pk;
    #pragma unroll
    for (int j = 0; j < 8; ++j)
      pk[j] = (c < 6) ? (short)f2bf(sV[c * 260 + k0 + j] * sScale[c]) : (short)0;
    *(short8*)&W3f[(size_t)gidx * 4096 + (size_t)ks * 512 + l * 8] = pk;
  }
}

// prep_x body: x = pf + [cos|sin](2pi qp·B), transpose-gather to Xg[g][b][i].
// 2x2 tile per iteration — rows (n,n+1) x cols (c,c+1), float2 pf loads.
static __device__ __forceinline__ void prep_x_body(
    int b, const float* __restrict__ qp, const float* __restrict__ pf,
    const float* __restrict__ Brff, unsigned short* __restrict__ Xg,
    float* sB, float* sQ, unsigned short* sX) {
  const int t = threadIdx.x;
  if (t < 720) sB[t] = Brff[t];
  if (t < 240) sQ[t] = qp[(size_t)b * 240 + t];
  __syncthreads();
  const float* pfb = pf + (size_t)b * 38400;
  #pragma unroll 2
  for (int idx = t; idx < 9600; idx += 1024) {
    int n2 = idx / 240;                      // 0..39  : n pair
    int c2 = idx - n2 * 240;                 // 0..239 : c pair
    int n  = n2 * 2, c = c2 * 2;
    int k  = (c < 240) ? c : c - 240;
    float bx0 = sB[k],       bx1 = sB[k + 1];
    float by0 = sB[240 + k], by1 = sB[241 + k];
    float bz0 = sB[480 + k], bz1 = sB[481 + k];
    float qx0 = sQ[n*3],   qy0 = sQ[n*3+1], qz0 = sQ[n*3+2];
    float qx1 = sQ[n*3+3], qy1 = sQ[n*3+4], qz1 = sQ[n*3+5];
    float d00 = qx0 * bx0 + qy0 * by0 + qz0 * bz0;   // (n,   c)
    float d01 = qx0 * bx1 + qy0 * by1 + qz0 * bz1;   // (n,   c+1)
    float d10 = qx1 * bx0 + qy1 * by0 + qz1 * bz0;   // (n+1, c)
    float d11 = qx1 * bx1 + qy1 * by1 + qz1 * bz1;   // (n+1, c+1)
    // v_sin/v_cos take revolutions: sin(2*pi*d) == v_sin(d)
    bool ucos = (c < 240);
    float f00 = ucos ? __builtin_amdgcn_cosf(d00) : __builtin_amdgcn_sinf(d00);
    float f01 = ucos ? __builtin_amdgcn_cosf(d01) : __builtin_amdgcn_sinf(d01);
    float f10 = ucos ? __builtin_amdgcn_cosf(d10) : __builtin_amdgcn_sinf(d10);
    float f11 = ucos ? __builtin_amdgcn_cosf(d11) : __builtin_amdgcn_sinf(d11);
    float2 p0 = *(const float2*)&pfb[n * 480 + c];         // 8B aligned (c even)
    float2 p1 = *(const float2*)&pfb[(n + 1) * 480 + c];
    unsigned int w0 = (unsigned int)f2bf(p0.x + f00)
                    | ((unsigned int)f2bf(p1.x + f10) << 16);   // col c: (n, n+1)
    unsigned int w1 = (unsigned int)f2bf(p0.y + f01)
                    | ((unsigned int)f2bf(p1.y + f11) << 16);   // col c+1
    *(unsigned int*)&sX[c * 82 + n]       = w0;
    *(unsigned int*)&sX[(c + 1) * 82 + n] = w1;
  }
  __syncthreads();
  for (int idx4 = t; idx4 < 9600; idx4 += 1024) {
    int g  = idx4 / 120;
    int i4 = idx4 - g * 120;
    int i  = i4 * 4;
    int cl = i / 80;
    int n  = i - cl * 80;
    const unsigned int* p = (const unsigned int*)&sX[(g * 6 + cl) * 82 + n];
    uint2v val = { p[0], p[1] };
    *(uint2v*)(Xg + ((size_t)g * BATCH + b) * 480 + i) = val;
  }
}

__global__ void __launch_bounds__(1024)
prep_all(const float* __restrict__ qp, const float* __restrict__ pf,
         const float* __restrict__ Brff,
         const float* __restrict__ v0, const float* __restrict__ g0,
         const float* __restrict__ v1, const float* __restrict__ g1,
         const float* __restrict__ v2, const float* __restrict__ g2,
         const float* __restrict__ v3, const float* __restrict__ g3,
         unsigned short* __restrict__ W0, unsigned short* __restrict__ W1,
         unsigned short* __restrict__ W2, unsigned short* __restrict__ W3f,
         unsigned short* __restrict__ Xg) {
  __shared__ float sMem[960];                      // sB(720) + sQ(240)
  __shared__ unsigned short sBig[480 * 82];        // sX / aliases sV
  const int bid = blockIdx.x;
  const int q = bid / 13, r = bid - q * 13;
  if (r < 8) {
    const int wb = q * 8 + r;
    float* sV = (float*)sBig;
    float* sScale = sMem;
    if      (wb < 1280) wfrag32_body<480, 512>(wb,        v0, g0, W0, sV, sScale);
    else if (wb < 2560) wfrag32_body<512, 512>(wb - 1280, v1, g1, W1, sV, sScale);
    else if (wb < 3200) wfrag32_body<512, 256>(wb - 2560, v2, g2, W2, sV, sScale);
    else if (wb < 3280) w3frag_body(wb - 3200, v3, g3, W3f, sV, sScale);
  } else {
    const int pb = q * 5 + (r - 8);
    if (pb < BATCH)
      prep_x_body(pb, qp, pf, Brff, Xg, sMem, sMem + 720, sBig);
  }
}

// ---------------------------------------------------------------------------
// mlp: M=128 rows/block, 16 waves (1024 thr), in-place LDS [128][SMLP]=133 KB,
// 1 block/CU, 4 waves/SIMD. 32x32x16 MFMA. N=512: 16 col strips (WN=16, MT=4);
// N=256: 8 strips x 2 row halves (WN=8, MT=2). NT=1 -> per step: MT a-reads
// (JIT), MT MFMAs sharing ONE B frag, depth-3 B prefetch (issue before MFMAs).
// ---------------------------------------------------------------------------
#define MLP_STEP16W(ksv, BB)                                                  \
  {                                                                           \
    const int ksc = (ksv);                                                    \
    short8 a[MT];                                                             \
    _Pragma("unroll")                                                         \
    for (int mt = 0; mt < MT; ++mt)                                           \
      a[mt] = *(const short8*)(aB + mt * 32 * SMLP + ksc * 16);               \
    short8 p0;                                                                \
    const bool pf_ok = (ksc + 3 < KS);                                        \
    if (pf_ok) p0 = *(const short8*)(wB + (size_t)(ksc + 3) * 512);           \
    __builtin_amdgcn_s_setprio(1);                                            \
    _Pragma("unroll")                                                         \
    for (int mt = 0; mt < MT; ++mt)                                           \
      acc[mt] = __builtin_amdgcn_mfma_f32_32x32x16_bf16(a[mt], BB, acc[mt], 0, 0, 0); \
    __builtin_amdgcn_s_setprio(0);                                            \
    if (pf_ok) BB = p0;                                                       \
  }

template<int K, int N, bool ACT>
static __device__ __forceinline__ void run_layer16w(
    unsigned short* __restrict__ s,
    const unsigned short* __restrict__ Wf, const float* __restrict__ bias,
    int wave, int lane) {
  constexpr int WN = N / 32;               // col strips: 16 (N=512) or 8 (N=256)
  constexpr int MT = WN / 4;               // m-tiles per wave: 4 or 2
  constexpr int KS = K / 16;               // 30 or 32
  constexpr int KB3 = (KS / 3) * 3;
  const int wn = wave & (WN - 1);
  const int wm = wave / WN;                // 0, or 0..1 for N=256
  const int nbase = wn * 32;
  const int lr = lane & 31, lh = lane >> 5;

  f32x16 acc[MT];
  #pragma unroll
  for (int mt = 0; mt < MT; ++mt)
    #pragma unroll
    for (int r = 0; r < 16; ++r) acc[mt][r] = 0.f;

  const unsigned short* aB = s + (wm * MT * 32 + lr) * SMLP + lh * 8;
  const unsigned short* wB = Wf + (size_t)wn * KS * 512 + lane * 8;

  short8 bb0 = *(const short8*)(wB);
  short8 bb1 = *(const short8*)(wB + 512);
  short8 bb2 = *(const short8*)(wB + 1024);

  #pragma unroll
  for (int k3 = 0; k3 < KS / 3; ++k3) {
    MLP_STEP16W(3 * k3,     bb0);
    MLP_STEP16W(3 * k3 + 1, bb1);
    MLP_STEP16W(3 * k3 + 2, bb2);
  }
  if (KS % 3 == 2) {                        // KS=32: two tail steps
    MLP_STEP16W(KB3,     bb0);
    MLP_STEP16W(KB3 + 1, bb1);
  }

  const float bv = bias[nbase + lr];        // loaded AFTER K-loop

  __syncthreads();   // all waves done READING s
  #pragma unroll
  for (int mt = 0; mt < MT; ++mt)
    #pragma unroll
    for (int r = 0; r < 16; ++r) {
      float val = acc[mt][r] + bv;
      if (ACT) val = (val >= 0.f) ? val : 0.01f * val;
      const int row = (wm * MT + mt) * 32 + (r & 3) + 8 * (r >> 2) + 4 * lh;
      s[row * SMLP + nbase + lr] = f2bf(val);
    }
  __syncthreads();   // writes visible before next layer reads
}

__global__ void __launch_bounds__(1024, 4)
mlp_kernel(const unsigned short* __restrict__ Xg,
           const unsigned short* __restrict__ W0, const unsigned short* __restrict__ W1,
           const unsigned short* __restrict__ W2, const unsigned short* __restrict__ W3f,
           const float* __restrict__ b0, const float* __restrict__ b1,
           const float* __restrict__ b2, const float* __restrict__ b3,
           float* __restrict__ out) {
  __shared__ unsigned short s[128 * SMLP];  // 133 KB -> 1 block/CU, 16 waves

  // XCD swizzle: bid%8 = XCD; each XCD walks its 10 groups' 16 tiles.
  const int bid   = blockIdx.x;
  const int xcd   = bid & 7;
  const int local = bid >> 3;               // 0..159
  const int g     = xcd * 10 + (local >> 4);
  const int tile  = local & 15;
  const int m0    = tile * 128;

  const int tid  = threadIdx.x, lane = tid & 63;
  const int wave = tid >> 6;                // 0..15

  // stage X tile [128][480]
  const unsigned short* Xs = Xg + ((size_t)g * BATCH + m0) * 480;
  for (int idx = tid; idx < 128 * 60; idx += 1024) {
    int row = idx / 60, c = idx - row * 60;
    *(short8*)&s[row * SMLP + c * 8] = *(const short8*)(Xs + (size_t)row * 480 + c * 8);
  }
  __syncthreads();

  run_layer16w<480, 512, true>(s, W0 + (size_t)g * 512 * 480, b0 + g * 512, wave, lane);
  run_layer16w<512, 512, true>(s, W1 + (size_t)g * 512 * 512, b1 + g * 512, wave, lane);
  run_layer16w<512, 256, true>(s, W2 + (size_t)g * 256 * 512, b2 + g * 256, wave, lane);

  // layer 4 via MFMA: [128x256] @ [256x16(pad 6)] ; waves 0-7, 16 rows each.
  if (wave < 8) {
    const int lr = lane & 15, lh = lane >> 4;
    const unsigned short* aB4 = s + (wave * 16 + lr) * SMLP + lh * 8;
    const unsigned short* w3  = W3f + (size_t)g * 4096 + lane * 8;
    f32x4 a4 = (f32x4){0.f, 0.f, 0.f, 0.f};
    #pragma unroll
    for (int kk = 0; kk < 8; ++kk) {
      short8 av  = *(const short8*)(aB4 + kk * 32);
      short8 wv8 = *(const short8*)(w3 + (size_t)kk * 512);
      a4 = __builtin_amdgcn_mfma_f32_16x16x32_bf16(av, wv8, a4, 0, 0, 0);
    }
    const int col = lane & 15;
    if (col < 6) {
      const float bias3 = b3[g * 6 + col];
      #pragma unroll
      for (int r = 0; r < 4; ++r)
        out[((size_t)(m0 + wave * 16 + lh * 4 + r) * VJ + g) * 6 + col] = a4[r] + bias3;
    }
  }
}

// ---------------------------------------------------------------------------
extern "C" void kernel_launch(void* const* d_in, const int* in_sizes, int n_in,
                              void* d_out, int out_size, void* d_ws, size_t ws_size,
                              hipStream_t stream) {
  const float* qp   = (const float*)d_in[0];
  const float* pf   = (const float*)d_in[1];
  const float* Brff = (const float*)d_in[2];
  const float* v0 = (const float*)d_in[3];  const float* g0 = (const float*)d_in[4];  const float* b0 = (const float*)d_in[5];
  const float* v1 = (const float*)d_in[6];  const float* g1 = (const float*)d_in[7];  const float* b1 = (const float*)d_in[8];
  const float* v2 = (const float*)d_in[9];  const float* g2 = (const float*)d_in[10]; const float* b2 = (const float*)d_in[11];
  const float* v3 = (const float*)d_in[12]; const float* g3 = (const float*)d_in[13]; const float* b3 = (const float*)d_in[14];

  unsigned short* W0  = (unsigned short*)d_ws;                // 32x32 frag layout
  unsigned short* W1  = W0 + (size_t)VJ * HD2 * FS;
  unsigned short* W2  = W1 + (size_t)VJ * HD2 * HD2;
  unsigned short* W3f = W2 + (size_t)VJ * HD  * HD2;          // 16x16 frags, 6->16 pad
  unsigned short* Xg  = W3f + (size_t)VJ * 4096;              // [80][2048][480]

  // 8:5 interleave (3280:2048 = 1.6 exactly): 410 chunks of 13 -> grid 5330.
  prep_all<<<dim3(5330), dim3(1024), 0, stream>>>(qp, pf, Brff,
                                                  v0, g0, v1, g1, v2, g2, v3, g3,
                                                  W0, W1, W2, W3f, Xg);
  mlp_kernel<<<dim3(VJ * 16), dim3(1024), 0, stream>>>(Xg, W0, W1, W2, W3f,
                                                       b0, b1, b2, b3, (float*)d_out);
}

// Round 19
// 375.913 us; speedup vs baseline: 1.0909x; 1.0909x over previous
//
#include <hip/hip_runtime.h>

// VposeFiled_Vjmlp: RFF encode + 80-group weight-norm MLP chain (480->512->512->256->6)
// R19 = R16 (best: 380us; mlp 233us) + merged cos/sin in prep_x: d = qp·B[k]
//       serves BOTH c=k (cos) and c=k+240 (sin) -> dots, sB reads, loop iters
//       all halve. Same trig/load/store per output; identical LDS pattern.
//       mlp untouched (R18's M=128/16w spilled AND doubled A-LDS; reverted).

typedef __attribute__((ext_vector_type(8)))  short short8;
typedef __attribute__((ext_vector_type(4)))  float f32x4;
typedef __attribute__((ext_vector_type(16))) float f32x16;
typedef __attribute__((ext_vector_type(2)))  unsigned int uint2v;

#define VJ    80
#define FS    480
#define HD2   512
#define HD    256
#define BATCH 2048
#define SMLP  520   // stride ushorts: 260 dw ≡ 4 (mod 32) -> ~2-way on 32-row b128 reads

static __device__ __forceinline__ unsigned short f2bf(float f) {
  unsigned int u = __builtin_bit_cast(unsigned int, f);
  u += 0x7FFFu + ((u >> 16) & 1u);          // round-to-nearest-even
  return (unsigned short)(u >> 16);
}

// ---------------------------------------------------------------------------
// Merged prep (1024 thr). 13-chunks: 8 weight-blocks + 5 prep_x-blocks.
// Weight blocks: [0,1280) W0, [1280,2560) W1, [2560,3200) W2 (32x32 frag pack),
// [3200,3280) W3 (16x16 frags, cols padded 6->16).
// 32x32 frag(nt,ks) = 512 ushorts: lane l elem j = W[nt*32+(l&31)][ks*16+(l>>5)*8+j]
// ---------------------------------------------------------------------------
template<int K, int RPG>
static __device__ __forceinline__ void wfrag32_body(
    int blk, const float* __restrict__ v, const float* __restrict__ gain,
    unsigned short* __restrict__ dst, float* sV, float* sScale) {
  constexpr int KS = K / 16;
  constexpr int KP = K + 4;
  const int t  = threadIdx.x;               // 0..1023
  const int n0 = blk * 32;
  const int g  = n0 / RPG;
  const int nt = (n0 % RPG) >> 5;

  const f32x4* v4 = (const f32x4*)(v + (size_t)n0 * K);
  for (int idx = t; idx < 32 * K / 4; idx += 1024) {
    int row = idx / (K / 4), rem = idx - row * (K / 4);
    *(f32x4*)&sV[row * KP + rem * 4] = v4[idx];
  }
  __syncthreads();

  const int wave = t >> 6, lane = t & 63;   // 16 waves
  for (int r = wave; r < 32; r += 16) {
    float s = 0.f;
    for (int k = lane; k < K; k += 64) { float x = sV[r * KP + k]; s += x * x; }
    #pragma unroll
    for (int off = 32; off > 0; off >>= 1) s += __shfl_down(s, off);
    if (lane == 0) sScale[r] = gain[n0 + r] / sqrtf(s);
  }
  __syncthreads();

  unsigned short* db = dst + (size_t)g * RPG * K + (size_t)nt * KS * 512;
  for (int o = t; o < KS * 64; o += 1024) {
    int ks = o >> 6, l = o & 63;
    int nl = l & 31, k0 = ks * 16 + ((l >> 5) << 3);
    float sc = sScale[nl];
    short8 pk;
    #pragma unroll
    for (int j = 0; j < 8; ++j) pk[j] = (short)f2bf(sV[nl * KP + k0 + j] * sc);
    *(short8*)&db[(size_t)ks * 512 + l * 8] = pk;
  }
}

// W3 per-group: 6 rows, K=256 -> 8 frags (16x16x32), cols padded to 16 w/ zeros.
static __device__ __forceinline__ void w3frag_body(
    int gidx, const float* __restrict__ v3, const float* __restrict__ g3,
    unsigned short* __restrict__ W3f, float* sV, float* sScale) {
  const int t = threadIdx.x;
  const f32x4* v4 = (const f32x4*)(v3 + (size_t)gidx * 6 * 256);
  if (t < 384) {
    int row = t >> 6, rem = t & 63;
    *(f32x4*)&sV[row * 260 + rem * 4] = v4[t];
  }
  __syncthreads();
  const int wave = t >> 6, lane = t & 63;
  if (wave < 6) {
    float s = 0.f;
    #pragma unroll
    for (int k = 0; k < 4; ++k) { float x = sV[wave * 260 + lane + k * 64]; s += x * x; }
    #pragma unroll
    for (int off = 32; off > 0; off >>= 1) s += __shfl_down(s, off);
    if (lane == 0) sScale[wave] = g3[gidx * 6 + wave] / sqrtf(s);
  }
  __syncthreads();
  if (t < 512) {
    int ks = t >> 6, l = t & 63;
    int c = l & 15, k0 = ks * 32 + ((l >> 4) << 3);
    short8 pk;
    #pragma unroll
    for (int j = 0; j < 8; ++j)
      pk[j] = (c < 6) ? (short)f2bf(sV[c * 260 + k0 + j] * sScale[c]) : (short)0;
    *(short8*)&W3f[(size_t)gidx * 4096 + (size_t)ks * 512 + l * 8] = pk;
  }
}

// prep_x body: x = pf + [cos|sin](2pi qp·B), transpose-gather to Xg[g][b][i].
// R19: merged cos/sin — d(n,k) feeds BOTH c=k (cos) and c=k+240 (sin).
// Tile: rows (n,n+1) x freq pair (k,k+1) -> 8 outputs per iter, 4800 iters.
static __device__ __forceinline__ void prep_x_body(
    int b, const float* __restrict__ qp, const float* __restrict__ pf,
    const float* __restrict__ Brff, unsigned short* __restrict__ Xg,
    float* sB, float* sQ, unsigned short* sX) {
  const int t = threadIdx.x;
  if (t < 720) sB[t] = Brff[t];
  if (t < 240) sQ[t] = qp[(size_t)b * 240 + t];
  __syncthreads();
  const float* pfb = pf + (size_t)b * 38400;
  #pragma unroll 2
  for (int idx = t; idx < 4800; idx += 1024) {
    int n2 = idx / 120;                      // 0..39  : joint pair
    int k2 = idx - n2 * 120;                 // 0..119 : freq pair (k-minor: coalesced pf)
    int n  = n2 * 2, k = k2 * 2;
    float bx0 = sB[k],       bx1 = sB[k + 1];
    float by0 = sB[240 + k], by1 = sB[241 + k];
    float bz0 = sB[480 + k], bz1 = sB[481 + k];
    float qx0 = sQ[n*3],   qy0 = sQ[n*3+1], qz0 = sQ[n*3+2];
    float qx1 = sQ[n*3+3], qy1 = sQ[n*3+4], qz1 = sQ[n*3+5];
    float d00 = qx0 * bx0 + qy0 * by0 + qz0 * bz0;   // (n,   k)
    float d01 = qx0 * bx1 + qy0 * by1 + qz0 * bz1;   // (n,   k+1)
    float d10 = qx1 * bx0 + qy1 * by0 + qz1 * bz0;   // (n+1, k)
    float d11 = qx1 * bx1 + qy1 * by1 + qz1 * bz1;   // (n+1, k+1)
    // v_sin/v_cos take revolutions: sin(2*pi*d) == v_sin(d); d serves cos AND sin
    float c00 = __builtin_amdgcn_cosf(d00), s00 = __builtin_amdgcn_sinf(d00);
    float c01 = __builtin_amdgcn_cosf(d01), s01 = __builtin_amdgcn_sinf(d01);
    float c10 = __builtin_amdgcn_cosf(d10), s10 = __builtin_amdgcn_sinf(d10);
    float c11 = __builtin_amdgcn_cosf(d11), s11 = __builtin_amdgcn_sinf(d11);
    float2 pc0 = *(const float2*)&pfb[n * 480 + k];            // cos cols (c = k)
    float2 pc1 = *(const float2*)&pfb[(n + 1) * 480 + k];
    float2 ps0 = *(const float2*)&pfb[n * 480 + 240 + k];      // sin cols (c = 240+k)
    float2 ps1 = *(const float2*)&pfb[(n + 1) * 480 + 240 + k];
    unsigned int wc0 = (unsigned int)f2bf(pc0.x + c00)
                     | ((unsigned int)f2bf(pc1.x + c10) << 16);
    unsigned int wc1 = (unsigned int)f2bf(pc0.y + c01)
                     | ((unsigned int)f2bf(pc1.y + c11) << 16);
    unsigned int ws0 = (unsigned int)f2bf(ps0.x + s00)
                     | ((unsigned int)f2bf(ps1.x + s10) << 16);
    unsigned int ws1 = (unsigned int)f2bf(ps0.y + s01)
                     | ((unsigned int)f2bf(ps1.y + s11) << 16);
    *(unsigned int*)&sX[k * 82 + n]         = wc0;
    *(unsigned int*)&sX[(k + 1) * 82 + n]   = wc1;
    *(unsigned int*)&sX[(240 + k) * 82 + n] = ws0;
    *(unsigned int*)&sX[(241 + k) * 82 + n] = ws1;
  }
  __syncthreads();
  for (int idx4 = t; idx4 < 9600; idx4 += 1024) {
    int g  = idx4 / 120;
    int i4 = idx4 - g * 120;
    int i  = i4 * 4;
    int cl = i / 80;
    int n  = i - cl * 80;
    const unsigned int* p = (const unsigned int*)&sX[(g * 6 + cl) * 82 + n];
    uint2v val = { p[0], p[1] };
    *(uint2v*)(Xg + ((size_t)g * BATCH + b) * 480 + i) = val;
  }
}

__global__ void __launch_bounds__(1024)
prep_all(const float* __restrict__ qp, const float* __restrict__ pf,
         const float* __restrict__ Brff,
         const float* __restrict__ v0, const float* __restrict__ g0,
         const float* __restrict__ v1, const float* __restrict__ g1,
         const float* __restrict__ v2, const float* __restrict__ g2,
         const float* __restrict__ v3, const float* __restrict__ g3,
         unsigned short* __restrict__ W0, unsigned short* __restrict__ W1,
         unsigned short* __restrict__ W2, unsigned short* __restrict__ W3f,
         unsigned short* __restrict__ Xg) {
  __shared__ float sMem[960];                      // sB(720) + sQ(240)
  __shared__ unsigned short sBig[480 * 82];        // sX / aliases sV
  const int bid = blockIdx.x;
  const int q = bid / 13, r = bid - q * 13;
  if (r < 8) {
    const int wb = q * 8 + r;
    float* sV = (float*)sBig;
    float* sScale = sMem;
    if      (wb < 1280) wfrag32_body<480, 512>(wb,        v0, g0, W0, sV, sScale);
    else if (wb < 2560) wfrag32_body<512, 512>(wb - 1280, v1, g1, W1, sV, sScale);
    else if (wb < 3200) wfrag32_body<512, 256>(wb - 2560, v2, g2, W2, sV, sScale);
    else if (wb < 3280) w3frag_body(wb - 3200, v3, g3, W3f, sV, sScale);
  } else {
    const int pb = q * 5 + (r - 8);
    if (pb < BATCH)
      prep_x_body(pb, qp, pf, Brff, Xg, sMem, sMem + 720, sBig);
  }
}

// ---------------------------------------------------------------------------
// mlp: R13/R16 exactly (measured best). M=64 rows/block, 8 waves, in-place LDS
// [64][SMLP] = 65 KB -> 2 blocks/CU (4 waves/SIMD — proven TLP optimum).
// 32x32x16 MFMA; wave wn owns cols [wn*64,+64) as NT n-tiles. acc f32x16[2][NT]
// (64 AGPR); depth-3 named B prefetch (bb0/bb1/bb2) issued before the MFMAs.
// ---------------------------------------------------------------------------
#define MLP_STEP32(ksv, BB)                                                   \
  {                                                                           \
    const int ksc = (ksv);                                                    \
    short8 a0 = *(const short8*)(aB + ksc * 16);                              \
    short8 a1 = *(const short8*)(aB + 32 * SMLP + ksc * 16);                  \
    short8 p0, p1;                                                            \
    const bool pf_ok = (ksc + 3 < KS);                                        \
    if (pf_ok) {                                                              \
      p0 = *(const short8*)(wB + ((size_t)0 * KS + ksc + 3) * 512);           \
      if (NT > 1) p1 = *(const short8*)(wB + ((size_t)1 * KS + ksc + 3) * 512); \
    }                                                                         \
    __builtin_amdgcn_s_setprio(1);                                            \
    _Pragma("unroll")                                                         \
    for (int nt = 0; nt < NT; ++nt)                                           \
      acc[0][nt] = __builtin_amdgcn_mfma_f32_32x32x16_bf16(a0, BB[nt], acc[0][nt], 0, 0, 0); \
    _Pragma("unroll")                                                         \
    for (int nt = 0; nt < NT; ++nt)                                           \
      acc[1][nt] = __builtin_amdgcn_mfma_f32_32x32x16_bf16(a1, BB[nt], acc[1][nt], 0, 0, 0); \
    __builtin_amdgcn_s_setprio(0);                                            \
    if (pf_ok) {                                                              \
      BB[0] = p0;                                                             \
      if (NT > 1) BB[1] = p1;                                                 \
    }                                                                         \
  }

template<int K, int N, bool ACT>
static __device__ __forceinline__ void run_layer32(
    unsigned short* __restrict__ s,
    const unsigned short* __restrict__ Wf, const float* __restrict__ bias,
    int wn, int lane) {
  constexpr int NT = N / 256;              // n-tiles per wave (2 or 1)
  constexpr int KS = K / 16;               // k16 steps (30 or 32)
  const int nbase = wn * (N / 8);
  const int lr = lane & 31, lh = lane >> 5;

  f32x16 acc[2][NT];
  #pragma unroll
  for (int mt = 0; mt < 2; ++mt)
    #pragma unroll
    for (int nt = 0; nt < NT; ++nt)
      #pragma unroll
      for (int r = 0; r < 16; ++r) acc[mt][nt][r] = 0.f;

  const unsigned short* aB = s + lr * SMLP + lh * 8;
  const unsigned short* wB = Wf + (size_t)(wn * NT) * KS * 512 + lane * 8;

  short8 bb0[NT], bb1[NT], bb2[NT];
  #pragma unroll
  for (int nt = 0; nt < NT; ++nt) bb0[nt] = *(const short8*)(wB + ((size_t)nt * KS    ) * 512);
  #pragma unroll
  for (int nt = 0; nt < NT; ++nt) bb1[nt] = *(const short8*)(wB + ((size_t)nt * KS + 1) * 512);
  #pragma unroll
  for (int nt = 0; nt < NT; ++nt) bb2[nt] = *(const short8*)(wB + ((size_t)nt * KS + 2) * 512);

  #pragma unroll
  for (int ks3 = 0; ks3 < KS / 3; ++ks3) {
    MLP_STEP32(3 * ks3,     bb0);
    MLP_STEP32(3 * ks3 + 1, bb1);
    MLP_STEP32(3 * ks3 + 2, bb2);
  }
  if (KS % 3 == 2) {                        // KS=32: two tail steps
    MLP_STEP32(KS - 2, bb0);
    MLP_STEP32(KS - 1, bb1);
  }

  float bv[NT];                             // bias loaded AFTER K-loop
  #pragma unroll
  for (int nt = 0; nt < NT; ++nt) bv[nt] = bias[nbase + nt * 32 + lr];

  __syncthreads();   // all waves done READING s
  #pragma unroll
  for (int mt = 0; mt < 2; ++mt)
    #pragma unroll
    for (int nt = 0; nt < NT; ++nt)
      #pragma unroll
      for (int r = 0; r < 16; ++r) {
        float val = acc[mt][nt][r] + bv[nt];
        if (ACT) val = (val >= 0.f) ? val : 0.01f * val;
        const int row = mt * 32 + (r & 3) + 8 * (r >> 2) + 4 * lh;
        s[row * SMLP + (nbase + nt * 32 + lr)] = f2bf(val);
      }
  __syncthreads();   // writes visible before next layer reads
}

__global__ void __launch_bounds__(512, 4)
mlp_kernel(const unsigned short* __restrict__ Xg,
           const unsigned short* __restrict__ W0, const unsigned short* __restrict__ W1,
           const unsigned short* __restrict__ W2, const unsigned short* __restrict__ W3f,
           const float* __restrict__ b0, const float* __restrict__ b1,
           const float* __restrict__ b2, const float* __restrict__ b3,
           float* __restrict__ out) {
  __shared__ unsigned short s[64 * SMLP];   // 65 KB -> 2 blocks/CU

  // XCD swizzle: bid%8 = XCD; each XCD walks its 10 groups' 32 tiles.
  const int bid   = blockIdx.x;
  const int xcd   = bid & 7;
  const int local = bid >> 3;                // 0..319
  const int g     = xcd * 10 + (local >> 5);
  const int tile  = local & 31;
  const int m0    = tile * 64;

  const int tid  = threadIdx.x, lane = tid & 63;
  const int wn   = tid >> 6;                 // col strip 0..7

  // stage X tile [64][480]
  const unsigned short* Xs = Xg + ((size_t)g * BATCH + m0) * 480;
  for (int idx = tid; idx < 64 * 60; idx += 512) {
    int row = idx / 60, c = idx - row * 60;
    *(short8*)&s[row * SMLP + c * 8] = *(const short8*)(Xs + (size_t)row * 480 + c * 8);
  }
  __syncthreads();

  run_layer32<480, 512, true>(s, W0 + (size_t)g * 512 * 480, b0 + g * 512, wn, lane);
  run_layer32<512, 512, true>(s, W1 + (size_t)g * 512 * 512, b1 + g * 512, wn, lane);
  run_layer32<512, 256, true>(s, W2 + (size_t)g * 256 * 512, b2 + g * 256, wn, lane);

  // layer 4 via MFMA: [64x256] @ [256x16(pad 6)] ; waves 0-3 each own 16 rows.
  if (wn < 4) {
    const int lr = lane & 15, lh = lane >> 4;
    const unsigned short* aB4 = s + (wn * 16 + lr) * SMLP + lh * 8;
    const unsigned short* w3  = W3f + (size_t)g * 4096 + lane * 8;
    f32x4 a4 = (f32x4){0.f, 0.f, 0.f, 0.f};
    #pragma unroll
    for (int kk = 0; kk < 8; ++kk) {
      short8 av  = *(const short8*)(aB4 + kk * 32);
      short8 wv8 = *(const short8*)(w3 + (size_t)kk * 512);
      a4 = __builtin_amdgcn_mfma_f32_16x16x32_bf16(av, wv8, a4, 0, 0, 0);
    }
    const int col = lane & 15;
    if (col < 6) {
      const float bias3 = b3[g * 6 + col];
      #pragma unroll
      for (int r = 0; r < 4; ++r)
        out[((size_t)(m0 + wn * 16 + lh * 4 + r) * VJ + g) * 6 + col] = a4[r] + bias3;
    }
  }
}

// ---------------------------------------------------------------------------
extern "C" void kernel_launch(void* const* d_in, const int* in_sizes, int n_in,
                              void* d_out, int out_size, void* d_ws, size_t ws_size,
                              hipStream_t stream) {
  const float* qp   = (const float*)d_in[0];
  const float* pf   = (const float*)d_in[1];
  const float* Brff = (const float*)d_in[2];
  const float* v0 = (const float*)d_in[3];  const float* g0 = (const float*)d_in[4];  const float* b0 = (const float*)d_in[5];
  const float* v1 = (const float*)d_in[6];  const float* g1 = (const float*)d_in[7];  const float* b1 = (const float*)d_in[8];
  const float* v2 = (const float*)d_in[9];  const float* g2 = (const float*)d_in[10]; const float* b2 = (const float*)d_in[11];
  const float* v3 = (const float*)d_in[12]; const float* g3 = (const float*)d_in[13]; const float* b3 = (const float*)d_in[14];

  unsigned short* W0  = (unsigned short*)d_ws;                // 32x32 frag layout
  unsigned short* W1  = W0 + (size_t)VJ * HD2 * FS;
  unsigned short* W2  = W1 + (size_t)VJ * HD2 * HD2;
  unsigned short* W3f = W2 + (size_t)VJ * HD  * HD2;          // 16x16 frags, 6->16 pad
  unsigned short* Xg  = W3f + (size_t)VJ * 4096;              // [80][2048][480]

  // 8:5 interleave (3280:2048 = 1.6 exactly): 410 chunks of 13 -> grid 5330.
  prep_all<<<dim3(5330), dim3(1024), 0, stream>>>(qp, pf, Brff,
                                                  v0, g0, v1, g1, v2, g2, v3, g3,
                                                  W0, W1, W2, W3f, Xg);
  mlp_kernel<<<dim3(VJ * 32), dim3(512), 0, stream>>>(Xg, W0, W1, W2, W3f,
                                                      b0, b1, b2, b3, (float*)d_out);
}